// Round 10
// baseline (280.035 us; speedup 1.0000x reference)
//
#include <hip/hip_runtime.h>
#include <hip/hip_cooperative_groups.h>

namespace cg = cooperative_groups;

typedef short bf16x8 __attribute__((ext_vector_type(8)));
typedef float f32x4 __attribute__((ext_vector_type(4)));

__device__ __forceinline__ unsigned short f2bf(float f) {
  union { float f; unsigned int u; } v; v.f = f;
  unsigned int r = v.u + 0x7FFFu + ((v.u >> 16) & 1u);
  return (unsigned short)(r >> 16);
}

__device__ __forceinline__ ushort4 cast4(float4 x) {
  ushort4 o; o.x = f2bf(x.x); o.y = f2bf(x.y); o.z = f2bf(x.z); o.w = f2bf(x.w);
  return o;
}

// One cooperative kernel: casts -> QKV GEMM -> attention -> out GEMM.
// 512 blocks x 256 threads (2 blocks/CU guaranteed: 9.2KB LDS, VGPR<=256).
__global__ __launch_bounds__(256, 2) void fused(
    const float* __restrict__ hs, const float* __restrict__ Wq,
    const float* __restrict__ Wk, const float* __restrict__ Wv,
    const float* __restrict__ Wo, unsigned short* __restrict__ hsb,
    unsigned short* __restrict__ Wqkvb, unsigned short* __restrict__ Wob,
    unsigned short* __restrict__ QKb, unsigned short* __restrict__ Vt,
    float* __restrict__ numAcc, float* __restrict__ denAcc,
    float* __restrict__ out) {
  cg::grid_group grid = cg::this_grid();
  __shared__ __align__(16) char smem[9216];
  const int tid = threadIdx.x;
  const int bid = blockIdx.x;
  const int w = tid >> 6, lane = tid & 63;
  const int lm = lane & 15, quad = lane >> 4;

  // ---- Stage A: fp32->bf16 casts + zero num/den accumulators ----
  for (int g = bid * 256 + tid; g < 566784; g += 131072) {
    if (g < 98304) {
      ((ushort4*)hsb)[g] = cast4(((const float4*)hs)[g]);
    } else if (g < 135168) {
      int i = g - 98304;
      ((ushort4*)Wqkvb)[i] = cast4(((const float4*)Wq)[i]);
    } else if (g < 172032) {
      int i = g - 135168;
      ((ushort4*)(Wqkvb + 147456))[i] = cast4(((const float4*)Wk)[i]);
    } else if (g < 319488) {
      int i = g - 172032;
      ((ushort4*)(Wqkvb + 294912))[i] = cast4(((const float4*)Wv)[i]);
    } else if (g < 466944) {
      int i = g - 319488;
      ((ushort4*)Wob)[i] = cast4(((const float4*)Wo)[i]);
    } else {  // numAcc(393216 f) + denAcc(6144 f) contiguous
      ((float4*)numAcc)[g - 466944] = make_float4(0.f, 0.f, 0.f, 0.f);
    }
  }
  grid.sync();

  // ---- Stage B: QKV GEMM, split-K x4; Q,K -> QKb[512][384], V -> Vt[768][512] ----
  f32x4* part = (f32x4*)smem;
  for (int task = bid; task < 2304; task += 512) {
    const int nTile = task % 72, mTile = task / 72;
    const int mt = mTile * 16, n0 = nTile * 16;
    const unsigned short* a_ptr = hsb + (mt + lm) * 768 + w * 192 + quad * 8;
    const unsigned short* b_ptr = Wqkvb + (n0 + lm) * 768 + w * 192 + quad * 8;
    f32x4 acc = {0.f, 0.f, 0.f, 0.f};
#pragma unroll
    for (int kb = 0; kb < 192; kb += 32) {
      bf16x8 av = *(const bf16x8*)(a_ptr + kb);
      bf16x8 bv = *(const bf16x8*)(b_ptr + kb);
      acc = __builtin_amdgcn_mfma_f32_16x16x32_bf16(av, bv, acc, 0, 0, 0);
    }
    part[w * 64 + lane] = acc;
    __syncthreads();
    if (w == 0) {
      f32x4 s = part[lane] + part[64 + lane] + part[128 + lane] + part[192 + lane];
      if (n0 < 384) {
#pragma unroll
        for (int r = 0; r < 4; ++r)
          QKb[(mt + quad * 4 + r) * 384 + n0 + lm] = f2bf(s[r]);
      } else {
        ushort4 o;
        o.x = f2bf(s[0]); o.y = f2bf(s[1]); o.z = f2bf(s[2]); o.w = f2bf(s[3]);
        *(ushort4*)&Vt[(n0 - 384 + lm) * 512 + mt + quad * 4] = o;
      }
    }
    __syncthreads();
  }
  grid.sync();

  // ---- Stage C: causal taylor attention, one (c,sb,h) tile per task ----
  unsigned short* scl = (unsigned short*)smem;  // [64][72] bf16, wave-private rows
  for (int task = bid; task < 432; task += 512) {
    int p = task % 36;
    const int h = task / 36;
    int c = 0;
    while (p >= c + 1) { p -= c + 1; ++c; }
    const int sb = p;
    const int t0 = c * 64, s0 = sb * 64;
    bf16x8 aq = {0, 0, 0, 0, 0, 0, 0, 0};
    if (quad < 2)
      aq = *(const bf16x8*)&QKb[(t0 + w * 16 + lm) * 384 + h * 16 + quad * 8];
    f32x4 qk[4];
#pragma unroll
    for (int sbt = 0; sbt < 4; ++sbt) {
      bf16x8 bk = {0, 0, 0, 0, 0, 0, 0, 0};
      if (quad < 2)
        bk = *(const bf16x8*)&QKb[(s0 + sbt * 16 + lm) * 384 + 192 + h * 16 + quad * 8];
      f32x4 z = {0.f, 0.f, 0.f, 0.f};
      qk[sbt] = __builtin_amdgcn_mfma_f32_16x16x32_bf16(aq, bk, z, 0, 0, 0);
    }
    float dsum[4] = {0.f, 0.f, 0.f, 0.f};
#pragma unroll
    for (int sbt = 0; sbt < 4; ++sbt) {
#pragma unroll
      for (int r = 0; r < 4; ++r) {
        const int tl = w * 16 + quad * 4 + r;
        const int sl = sbt * 16 + lm;
        float x = qk[sbt][r];
        float val = (s0 + sl <= t0 + tl) ? 1.f + 0.25f * x + 0.03125f * x * x : 0.f;
        dsum[r] += val;
        scl[tl * 72 + sl] = f2bf(val);
      }
    }
    f32x4 av4[4] = {{0.f,0.f,0.f,0.f},{0.f,0.f,0.f,0.f},{0.f,0.f,0.f,0.f},{0.f,0.f,0.f,0.f}};
    const unsigned short* vbase = Vt + (h * 64 + lm) * 512;
#pragma unroll
    for (int kb = 0; kb < 2; ++kb) {
      bf16x8 a = *(const bf16x8*)&scl[(w * 16 + lm) * 72 + kb * 32 + quad * 8];
#pragma unroll
      for (int dt = 0; dt < 4; ++dt) {
        bf16x8 b = *(const bf16x8*)&vbase[dt * 16 * 512 + s0 + kb * 32 + quad * 8];
        av4[dt] = __builtin_amdgcn_mfma_f32_16x16x32_bf16(a, b, av4[dt], 0, 0, 0);
      }
    }
#pragma unroll
    for (int r = 0; r < 4; ++r) {
      float v = dsum[r];
      v += __shfl_xor(v, 1); v += __shfl_xor(v, 2);
      v += __shfl_xor(v, 4); v += __shfl_xor(v, 8);
      if (lm == 0) atomicAdd(&denAcc[(t0 + w * 16 + quad * 4 + r) * 12 + h], v);
    }
#pragma unroll
    for (int dt = 0; dt < 4; ++dt)
#pragma unroll
      for (int r = 0; r < 4; ++r)
        atomicAdd(&numAcc[(t0 + w * 16 + quad * 4 + r) * 768 + h * 64 + dt * 16 + lm],
                  av4[dt][r]);
    __syncthreads();
  }
  grid.sync();

  // ---- Stage D: out = (num/den) @ Wo^T, split-K x4, fused divide+cast ----
  for (int task = bid; task < 1536; task += 512) {
    const int nTile = task % 48, mTile = task / 48;
    const int mt = mTile * 16, nt = nTile * 16;
    const int t = mt + lm;
    f32x4 acc = {0.f, 0.f, 0.f, 0.f};
#pragma unroll
    for (int kb = 0; kb < 192; kb += 32) {
      const int k0 = w * 192 + kb + quad * 8;
      const int hh = k0 >> 6;
      float inv = 1.f / (denAcc[t * 12 + hh] + 1e-12f);
      float4 x0 = *(const float4*)&numAcc[t * 768 + k0];
      float4 x1 = *(const float4*)&numAcc[t * 768 + k0 + 4];
      bf16x8 a;
      a[0] = f2bf(x0.x * inv); a[1] = f2bf(x0.y * inv);
      a[2] = f2bf(x0.z * inv); a[3] = f2bf(x0.w * inv);
      a[4] = f2bf(x1.x * inv); a[5] = f2bf(x1.y * inv);
      a[6] = f2bf(x1.z * inv); a[7] = f2bf(x1.w * inv);
      bf16x8 bv = *(const bf16x8*)&Wob[(nt + lm) * 768 + k0];
      acc = __builtin_amdgcn_mfma_f32_16x16x32_bf16(a, bv, acc, 0, 0, 0);
    }
    part[w * 64 + lane] = acc;
    __syncthreads();
    if (w == 0) {
      f32x4 s = part[lane] + part[64 + lane] + part[128 + lane] + part[192 + lane];
#pragma unroll
      for (int r = 0; r < 4; ++r)
        out[(mt + quad * 4 + r) * 768 + nt + lm] = s[r];
    }
    __syncthreads();
  }
}

extern "C" void kernel_launch(void* const* d_in, const int* in_sizes, int n_in,
                              void* d_out, int out_size, void* d_ws, size_t ws_size,
                              hipStream_t stream) {
  const float* hs = (const float*)d_in[0];
  const float* Wq = (const float*)d_in[1];
  const float* Wk = (const float*)d_in[2];
  const float* Wv = (const float*)d_in[3];
  const float* Wo = (const float*)d_in[4];
  float* out = (float*)d_out;
  float* ws = (float*)d_ws;

  float* numAcc = ws;                                      // 393216 f
  float* denAcc = ws + 393216;                             // 6144 f (contiguous!)
  unsigned short* hsb   = (unsigned short*)(ws + 399360);  // 393216 us
  unsigned short* Wqkvb = hsb + 393216;                    // 884736 us
  unsigned short* Wob   = Wqkvb + 884736;                  // 589824 us
  unsigned short* QKb   = Wob + 589824;                    // 196608 us
  unsigned short* Vt    = QKb + 196608;                    // 393216 us

  void* args[] = {(void*)&hs, (void*)&Wq, (void*)&Wk, (void*)&Wv, (void*)&Wo,
                  (void*)&hsb, (void*)&Wqkvb, (void*)&Wob, (void*)&QKb,
                  (void*)&Vt, (void*)&numAcc, (void*)&denAcc, (void*)&out};
  hipLaunchCooperativeKernel((const void*)fused, dim3(512), dim3(256), args, 0,
                             stream);
}

// Round 11
// 111.631 us; speedup vs baseline: 2.5086x; 2.5086x over previous
//
#include <hip/hip_runtime.h>

typedef short bf16x8 __attribute__((ext_vector_type(8)));
typedef float f32x4 __attribute__((ext_vector_type(4)));

__device__ __forceinline__ unsigned short f2bf(float f) {
  union { float f; unsigned int u; } v; v.f = f;
  unsigned int r = v.u + 0x7FFFu + ((v.u >> 16) & 1u);
  return (unsigned short)(r >> 16);
}

// ---- one-pass fp32->bf16 casts + zero num/den accumulators ----
__global__ __launch_bounds__(256) void prep(
    const float* __restrict__ hs, const float* __restrict__ Wq,
    const float* __restrict__ Wk, const float* __restrict__ Wv,
    const float* __restrict__ Wo, unsigned short* __restrict__ hsb,
    unsigned short* __restrict__ Wqkvb, unsigned short* __restrict__ Wob,
    float* __restrict__ numAcc) {
  int b = blockIdx.x;
  const float* src; unsigned short* dst; int base;
  if (b < 384)       { src = hs; dst = hsb;            base = b * 1024; }
  else if (b < 528)  { src = Wq; dst = Wqkvb;          base = (b - 384) * 1024; }
  else if (b < 672)  { src = Wk; dst = Wqkvb + 147456; base = (b - 528) * 1024; }
  else if (b < 1248) { src = Wv; dst = Wqkvb + 294912; base = (b - 672) * 1024; }
  else if (b < 1824) { src = Wo; dst = Wob;            base = (b - 1248) * 1024; }
  else {  // zero numAcc(393216 f) + denAcc(6144 f) contiguous = 99840 float4
    int i = (b - 1824) * 256 + threadIdx.x;
    ((float4*)numAcc)[i] = make_float4(0.f, 0.f, 0.f, 0.f);
    return;
  }
  int i = base + threadIdx.x * 4;
  float4 x = *(const float4*)&src[i];
  ushort4 o;
  o.x = f2bf(x.x); o.y = f2bf(x.y); o.z = f2bf(x.z); o.w = f2bf(x.w);
  *(ushort4*)&dst[i] = o;
}

// ---- QKV GEMM, split-K x4, bf16 in. Q,K -> QKb[512][384]; V -> Vt[768][512] ----
__global__ __launch_bounds__(256) void gemm_qkv(
    const unsigned short* __restrict__ A, const unsigned short* __restrict__ B,
    unsigned short* __restrict__ QKb, unsigned short* __restrict__ Vt) {
  __shared__ f32x4 part[4][64];
  const int tid = threadIdx.x;
  const int w = tid >> 6, lane = tid & 63;
  const int lm = lane & 15, quad = lane >> 4;
  const int mt = blockIdx.y * 16;
  const int n0 = blockIdx.x * 16;
  const int kw = w * 192;
  const unsigned short* a_ptr = A + (mt + lm) * 768 + kw + quad * 8;
  const unsigned short* b_ptr = B + (n0 + lm) * 768 + kw + quad * 8;
  f32x4 acc = {0.f, 0.f, 0.f, 0.f};
#pragma unroll
  for (int kb = 0; kb < 192; kb += 32) {
    bf16x8 av = *(const bf16x8*)(a_ptr + kb);
    bf16x8 bv = *(const bf16x8*)(b_ptr + kb);
    acc = __builtin_amdgcn_mfma_f32_16x16x32_bf16(av, bv, acc, 0, 0, 0);
  }
  part[w][lane] = acc;
  __syncthreads();
  if (w == 0) {
    f32x4 s = part[0][lane] + part[1][lane] + part[2][lane] + part[3][lane];
    if (n0 < 384) {
#pragma unroll
      for (int r = 0; r < 4; ++r)
        QKb[(mt + quad * 4 + r) * 384 + n0 + lm] = f2bf(s[r]);
    } else {
      ushort4 o;
      o.x = f2bf(s[0]); o.y = f2bf(s[1]); o.z = f2bf(s[2]); o.w = f2bf(s[3]);
      *(ushort4*)&Vt[(n0 - 384 + lm) * 512 + mt + quad * 4] = o;
    }
  }
}

// ---- causal taylor attention: one (c,sb,h) tile per block, 432 blocks.
// Barrier-free: score-LDS rows are wave-private; V from global Vt; atomics out.
__global__ __launch_bounds__(256) void attn(
    const unsigned short* __restrict__ QKb, const unsigned short* __restrict__ Vt,
    float* __restrict__ numAcc, float* __restrict__ denAcc) {
  int p = blockIdx.x;
  const int h = blockIdx.y, tid = threadIdx.x;
  int c = 0;
  while (p >= c + 1) { p -= c + 1; ++c; }
  const int sb = p;
  const int t0 = c * 64, s0 = sb * 64;
  __shared__ __align__(16) unsigned short scl[64 * 72];
  const int w = tid >> 6, lane = tid & 63;
  const int lm = lane & 15, quad = lane >> 4;
  bf16x8 aq = {0, 0, 0, 0, 0, 0, 0, 0};
  if (quad < 2)
    aq = *(const bf16x8*)&QKb[(t0 + w * 16 + lm) * 384 + h * 16 + quad * 8];
  f32x4 qk[4];
#pragma unroll
  for (int sbt = 0; sbt < 4; ++sbt) {
    bf16x8 bk = {0, 0, 0, 0, 0, 0, 0, 0};
    if (quad < 2)
      bk = *(const bf16x8*)&QKb[(s0 + sbt * 16 + lm) * 384 + 192 + h * 16 + quad * 8];
    f32x4 z = {0.f, 0.f, 0.f, 0.f};
    qk[sbt] = __builtin_amdgcn_mfma_f32_16x16x32_bf16(aq, bk, z, 0, 0, 0);
  }
  float dsum[4] = {0.f, 0.f, 0.f, 0.f};
#pragma unroll
  for (int sbt = 0; sbt < 4; ++sbt) {
#pragma unroll
    for (int r = 0; r < 4; ++r) {
      const int tl = w * 16 + quad * 4 + r;
      const int sl = sbt * 16 + lm;
      float x = qk[sbt][r];
      float val = (s0 + sl <= t0 + tl) ? 1.f + 0.25f * x + 0.03125f * x * x : 0.f;
      dsum[r] += val;
      scl[tl * 72 + sl] = f2bf(val);
    }
  }
  f32x4 av[4] = {{0.f,0.f,0.f,0.f},{0.f,0.f,0.f,0.f},{0.f,0.f,0.f,0.f},{0.f,0.f,0.f,0.f}};
  const unsigned short* vbase = Vt + (h * 64 + lm) * 512;
#pragma unroll
  for (int kb = 0; kb < 2; ++kb) {
    bf16x8 a = *(const bf16x8*)&scl[(w * 16 + lm) * 72 + kb * 32 + quad * 8];
#pragma unroll
    for (int dt = 0; dt < 4; ++dt) {
      bf16x8 b = *(const bf16x8*)&vbase[dt * 16 * 512 + s0 + kb * 32 + quad * 8];
      av[dt] = __builtin_amdgcn_mfma_f32_16x16x32_bf16(a, b, av[dt], 0, 0, 0);
    }
  }
#pragma unroll
  for (int r = 0; r < 4; ++r) {
    float v = dsum[r];
    v += __shfl_xor(v, 1); v += __shfl_xor(v, 2);
    v += __shfl_xor(v, 4); v += __shfl_xor(v, 8);
    if (lm == 0) atomicAdd(&denAcc[(t0 + w * 16 + quad * 4 + r) * 12 + h], v);
  }
#pragma unroll
  for (int dt = 0; dt < 4; ++dt)
#pragma unroll
    for (int r = 0; r < 4; ++r)
      atomicAdd(&numAcc[(t0 + w * 16 + quad * 4 + r) * 768 + h * 64 + dt * 16 + lm],
                av[dt][r]);
}

// ---- out GEMM, split-K x4, fused y = num/den on the A-fragment ----
__global__ __launch_bounds__(256) void gemm_out(
    const float* __restrict__ numAcc, const float* __restrict__ denAcc,
    const unsigned short* __restrict__ Wob, float* __restrict__ out) {
  __shared__ f32x4 part[4][64];
  const int tid = threadIdx.x;
  const int w = tid >> 6, lane = tid & 63;
  const int lm = lane & 15, quad = lane >> 4;
  const int mt = blockIdx.y * 16;
  const int nt = blockIdx.x * 16;
  const int t = mt + lm;
  const int kw = w * 192;
  f32x4 acc = {0.f, 0.f, 0.f, 0.f};
#pragma unroll
  for (int kb = 0; kb < 192; kb += 32) {
    int k0 = kw + kb + quad * 8;
    int hh = k0 >> 6;
    float inv = 1.f / (denAcc[t * 12 + hh] + 1e-12f);
    float4 x0 = *(const float4*)&numAcc[t * 768 + k0];
    float4 x1 = *(const float4*)&numAcc[t * 768 + k0 + 4];
    bf16x8 a;
    a[0] = f2bf(x0.x * inv); a[1] = f2bf(x0.y * inv);
    a[2] = f2bf(x0.z * inv); a[3] = f2bf(x0.w * inv);
    a[4] = f2bf(x1.x * inv); a[5] = f2bf(x1.y * inv);
    a[6] = f2bf(x1.z * inv); a[7] = f2bf(x1.w * inv);
    bf16x8 bv = *(const bf16x8*)&Wob[(nt + lm) * 768 + k0];
    acc = __builtin_amdgcn_mfma_f32_16x16x32_bf16(a, bv, acc, 0, 0, 0);
  }
  part[w][lane] = acc;
  __syncthreads();
  if (w == 0) {
    f32x4 s = part[0][lane] + part[1][lane] + part[2][lane] + part[3][lane];
#pragma unroll
    for (int r = 0; r < 4; ++r)
      out[(mt + quad * 4 + r) * 768 + nt + lm] = s[r];
  }
}

extern "C" void kernel_launch(void* const* d_in, const int* in_sizes, int n_in,
                              void* d_out, int out_size, void* d_ws, size_t ws_size,
                              hipStream_t stream) {
  const float* hs = (const float*)d_in[0];
  const float* Wq = (const float*)d_in[1];
  const float* Wk = (const float*)d_in[2];
  const float* Wv = (const float*)d_in[3];
  const float* Wo = (const float*)d_in[4];
  float* out = (float*)d_out;
  float* ws = (float*)d_ws;

  float* numAcc = ws;                                      // 393216 f
  float* denAcc = ws + 393216;                             // 6144 f (contiguous)
  unsigned short* hsb   = (unsigned short*)(ws + 399360);  // 393216 us
  unsigned short* Wqkvb = hsb + 393216;                    // 884736 us
  unsigned short* Wob   = Wqkvb + 884736;                  // 589824 us
  unsigned short* QKb   = Wob + 589824;                    // 196608 us
  unsigned short* Vt    = QKb + 196608;                    // 393216 us

  // casts + accumulator zeroing
  prep<<<dim3(2214), 256, 0, stream>>>(hs, Wq, Wk, Wv, Wo, hsb, Wqkvb, Wob, numAcc);
  // QKV projections; V emitted transposed
  gemm_qkv<<<dim3(72, 32), 256, 0, stream>>>(hsb, Wqkvb, QKb, Vt);
  // causal taylor attention partials (432 blocks, barrier-free, atomics)
  attn<<<dim3(36, 12), 256, 0, stream>>>(QKb, Vt, numAcc, denAcc);
  // out = (num/den) @ Wo^T
  gemm_out<<<dim3(48, 32), 256, 0, stream>>>(numAcc, denAcc, Wob, out);
}

// Round 12
// 105.176 us; speedup vs baseline: 2.6625x; 1.0614x over previous
//
#include <hip/hip_runtime.h>

typedef short bf16x8 __attribute__((ext_vector_type(8)));
typedef float f32x4 __attribute__((ext_vector_type(4)));

__device__ __forceinline__ unsigned short f2bf(float f) {
  union { float f; unsigned int u; } v; v.f = f;
  unsigned int r = v.u + 0x7FFFu + ((v.u >> 16) & 1u);
  return (unsigned short)(r >> 16);
}

// ---- one-pass fp32->bf16 casts + zero num/den accumulators ----
__global__ __launch_bounds__(256) void prep(
    const float* __restrict__ hs, const float* __restrict__ Wq,
    const float* __restrict__ Wk, const float* __restrict__ Wv,
    const float* __restrict__ Wo, unsigned short* __restrict__ hsb,
    unsigned short* __restrict__ Wqkvb, unsigned short* __restrict__ Wob,
    float* __restrict__ numAcc) {
  int b = blockIdx.x;
  const float* src; unsigned short* dst; int base;
  if (b < 384)       { src = hs; dst = hsb;            base = b * 1024; }
  else if (b < 528)  { src = Wq; dst = Wqkvb;          base = (b - 384) * 1024; }
  else if (b < 672)  { src = Wk; dst = Wqkvb + 147456; base = (b - 528) * 1024; }
  else if (b < 1248) { src = Wv; dst = Wqkvb + 294912; base = (b - 672) * 1024; }
  else if (b < 1824) { src = Wo; dst = Wob;            base = (b - 1248) * 1024; }
  else {  // zero numAcc(393216 f) + denAcc(6144 f) contiguous = 99840 float4
    int i = (b - 1824) * 256 + threadIdx.x;
    ((float4*)numAcc)[i] = make_float4(0.f, 0.f, 0.f, 0.f);
    return;
  }
  int i = base + threadIdx.x * 4;
  float4 x = *(const float4*)&src[i];
  ushort4 o;
  o.x = f2bf(x.x); o.y = f2bf(x.y); o.z = f2bf(x.z); o.w = f2bf(x.w);
  *(ushort4*)&dst[i] = o;
}

// ---- QKV GEMM: 16(M)x32(N) tile, split-K x4, shared A-fragment.
// Q,K -> QKb[512][384]; V -> Vt[768][512] (transposed).
__global__ __launch_bounds__(256) void gemm_qkv(
    const unsigned short* __restrict__ A, const unsigned short* __restrict__ B,
    unsigned short* __restrict__ QKb, unsigned short* __restrict__ Vt) {
  __shared__ f32x4 part[4][2][64];
  const int tid = threadIdx.x;
  const int w = tid >> 6, lane = tid & 63;
  const int lm = lane & 15, quad = lane >> 4;
  const int mt = blockIdx.y * 16;
  const int n0 = blockIdx.x * 32;
  const int kw = w * 192;
  const unsigned short* a_ptr = A + (mt + lm) * 768 + kw + quad * 8;
  const unsigned short* b_ptr = B + (n0 + lm) * 768 + kw + quad * 8;
  f32x4 acc0 = {0.f, 0.f, 0.f, 0.f}, acc1 = {0.f, 0.f, 0.f, 0.f};
#pragma unroll
  for (int kb = 0; kb < 192; kb += 32) {
    bf16x8 av = *(const bf16x8*)(a_ptr + kb);
    bf16x8 b0 = *(const bf16x8*)(b_ptr + kb);
    bf16x8 b1 = *(const bf16x8*)(b_ptr + 16 * 768 + kb);
    acc0 = __builtin_amdgcn_mfma_f32_16x16x32_bf16(av, b0, acc0, 0, 0, 0);
    acc1 = __builtin_amdgcn_mfma_f32_16x16x32_bf16(av, b1, acc1, 0, 0, 0);
  }
  part[w][0][lane] = acc0;
  part[w][1][lane] = acc1;
  __syncthreads();
  if (w < 2) {
    const int n = n0 + w * 16;
    f32x4 s = part[0][w][lane] + part[1][w][lane] + part[2][w][lane] + part[3][w][lane];
    if (n < 384) {
#pragma unroll
      for (int r = 0; r < 4; ++r)
        QKb[(mt + quad * 4 + r) * 384 + n + lm] = f2bf(s[r]);
    } else {
      ushort4 o;
      o.x = f2bf(s[0]); o.y = f2bf(s[1]); o.z = f2bf(s[2]); o.w = f2bf(s[3]);
      *(ushort4*)&Vt[(n - 384 + lm) * 512 + mt + quad * 4] = o;
    }
  }
}

// ---- causal taylor attention: one (c,sb,h) tile per block, 432 blocks.
// Barrier-free: score-LDS rows are wave-private; V from global Vt; atomics out.
__global__ __launch_bounds__(256) void attn(
    const unsigned short* __restrict__ QKb, const unsigned short* __restrict__ Vt,
    float* __restrict__ numAcc, float* __restrict__ denAcc) {
  int p = blockIdx.x;
  const int h = blockIdx.y, tid = threadIdx.x;
  int c = 0;
  while (p >= c + 1) { p -= c + 1; ++c; }
  const int sb = p;
  const int t0 = c * 64, s0 = sb * 64;
  __shared__ __align__(16) unsigned short scl[64 * 72];
  const int w = tid >> 6, lane = tid & 63;
  const int lm = lane & 15, quad = lane >> 4;
  bf16x8 aq = {0, 0, 0, 0, 0, 0, 0, 0};
  if (quad < 2)
    aq = *(const bf16x8*)&QKb[(t0 + w * 16 + lm) * 384 + h * 16 + quad * 8];
  f32x4 qk[4];
#pragma unroll
  for (int sbt = 0; sbt < 4; ++sbt) {
    bf16x8 bk = {0, 0, 0, 0, 0, 0, 0, 0};
    if (quad < 2)
      bk = *(const bf16x8*)&QKb[(s0 + sbt * 16 + lm) * 384 + 192 + h * 16 + quad * 8];
    f32x4 z = {0.f, 0.f, 0.f, 0.f};
    qk[sbt] = __builtin_amdgcn_mfma_f32_16x16x32_bf16(aq, bk, z, 0, 0, 0);
  }
  float dsum[4] = {0.f, 0.f, 0.f, 0.f};
#pragma unroll
  for (int sbt = 0; sbt < 4; ++sbt) {
#pragma unroll
    for (int r = 0; r < 4; ++r) {
      const int tl = w * 16 + quad * 4 + r;
      const int sl = sbt * 16 + lm;
      float x = qk[sbt][r];
      float val = (s0 + sl <= t0 + tl) ? 1.f + 0.25f * x + 0.03125f * x * x : 0.f;
      dsum[r] += val;
      scl[tl * 72 + sl] = f2bf(val);
    }
  }
  f32x4 av[4] = {{0.f,0.f,0.f,0.f},{0.f,0.f,0.f,0.f},{0.f,0.f,0.f,0.f},{0.f,0.f,0.f,0.f}};
  const unsigned short* vbase = Vt + (h * 64 + lm) * 512;
#pragma unroll
  for (int kb = 0; kb < 2; ++kb) {
    bf16x8 a = *(const bf16x8*)&scl[(w * 16 + lm) * 72 + kb * 32 + quad * 8];
#pragma unroll
    for (int dt = 0; dt < 4; ++dt) {
      bf16x8 b = *(const bf16x8*)&vbase[dt * 16 * 512 + s0 + kb * 32 + quad * 8];
      av[dt] = __builtin_amdgcn_mfma_f32_16x16x32_bf16(a, b, av[dt], 0, 0, 0);
    }
  }
#pragma unroll
  for (int r = 0; r < 4; ++r) {
    float v = dsum[r];
    v += __shfl_xor(v, 1); v += __shfl_xor(v, 2);
    v += __shfl_xor(v, 4); v += __shfl_xor(v, 8);
    if (lm == 0) atomicAdd(&denAcc[(t0 + w * 16 + quad * 4 + r) * 12 + h], v);
  }
#pragma unroll
  for (int dt = 0; dt < 4; ++dt)
#pragma unroll
    for (int r = 0; r < 4; ++r)
      atomicAdd(&numAcc[(t0 + w * 16 + quad * 4 + r) * 768 + h * 64 + dt * 16 + lm],
                av[dt][r]);
}

// ---- out GEMM: 16x32 tile, split-K x4, fused divide+cast (A shared) ----
__global__ __launch_bounds__(256) void gemm_out(
    const float* __restrict__ numAcc, const float* __restrict__ denAcc,
    const unsigned short* __restrict__ Wob, float* __restrict__ out) {
  __shared__ f32x4 part[4][2][64];
  const int tid = threadIdx.x;
  const int w = tid >> 6, lane = tid & 63;
  const int lm = lane & 15, quad = lane >> 4;
  const int mt = blockIdx.y * 16;
  const int n0 = blockIdx.x * 32;
  const int t = mt + lm;
  const int kw = w * 192;
  f32x4 acc0 = {0.f, 0.f, 0.f, 0.f}, acc1 = {0.f, 0.f, 0.f, 0.f};
#pragma unroll
  for (int kb = 0; kb < 192; kb += 32) {
    int k0 = kw + kb + quad * 8;
    int hh = k0 >> 6;
    float inv = 1.f / (denAcc[t * 12 + hh] + 1e-12f);
    float4 x0 = *(const float4*)&numAcc[t * 768 + k0];
    float4 x1 = *(const float4*)&numAcc[t * 768 + k0 + 4];
    bf16x8 a;
    a[0] = f2bf(x0.x * inv); a[1] = f2bf(x0.y * inv);
    a[2] = f2bf(x0.z * inv); a[3] = f2bf(x0.w * inv);
    a[4] = f2bf(x1.x * inv); a[5] = f2bf(x1.y * inv);
    a[6] = f2bf(x1.z * inv); a[7] = f2bf(x1.w * inv);
    bf16x8 b0 = *(const bf16x8*)&Wob[(n0 + lm) * 768 + k0];
    bf16x8 b1 = *(const bf16x8*)&Wob[(n0 + 16 + lm) * 768 + k0];
    acc0 = __builtin_amdgcn_mfma_f32_16x16x32_bf16(a, b0, acc0, 0, 0, 0);
    acc1 = __builtin_amdgcn_mfma_f32_16x16x32_bf16(a, b1, acc1, 0, 0, 0);
  }
  part[w][0][lane] = acc0;
  part[w][1][lane] = acc1;
  __syncthreads();
  if (w < 2) {
    const int n = n0 + w * 16;
    f32x4 s = part[0][w][lane] + part[1][w][lane] + part[2][w][lane] + part[3][w][lane];
#pragma unroll
    for (int r = 0; r < 4; ++r)
      out[(mt + quad * 4 + r) * 768 + n + lm] = s[r];
  }
}

extern "C" void kernel_launch(void* const* d_in, const int* in_sizes, int n_in,
                              void* d_out, int out_size, void* d_ws, size_t ws_size,
                              hipStream_t stream) {
  const float* hs = (const float*)d_in[0];
  const float* Wq = (const float*)d_in[1];
  const float* Wk = (const float*)d_in[2];
  const float* Wv = (const float*)d_in[3];
  const float* Wo = (const float*)d_in[4];
  float* out = (float*)d_out;
  float* ws = (float*)d_ws;

  float* numAcc = ws;                                      // 393216 f
  float* denAcc = ws + 393216;                             // 6144 f (contiguous)
  unsigned short* hsb   = (unsigned short*)(ws + 399360);  // 393216 us
  unsigned short* Wqkvb = hsb + 393216;                    // 884736 us
  unsigned short* Wob   = Wqkvb + 884736;                  // 589824 us
  unsigned short* QKb   = Wob + 589824;                    // 196608 us
  unsigned short* Vt    = QKb + 196608;                    // 393216 us

  // casts + accumulator zeroing
  prep<<<dim3(2214), 256, 0, stream>>>(hs, Wq, Wk, Wv, Wo, hsb, Wqkvb, Wob, numAcc);
  // QKV projections; V emitted transposed (16x32 tiles)
  gemm_qkv<<<dim3(36, 32), 256, 0, stream>>>(hsb, Wqkvb, QKb, Vt);
  // causal taylor attention partials (432 blocks, barrier-free, atomics)
  attn<<<dim3(36, 12), 256, 0, stream>>>(QKb, Vt, numAcc, denAcc);
  // out = (num/den) @ Wo^T (16x32 tiles)
  gemm_out<<<dim3(24, 32), 256, 0, stream>>>(numAcc, denAcc, Wob, out);
}

// Round 13
// 103.851 us; speedup vs baseline: 2.6965x; 1.0128x over previous
//
#include <hip/hip_runtime.h>

typedef short bf16x8 __attribute__((ext_vector_type(8)));
typedef float f32x4 __attribute__((ext_vector_type(4)));

__device__ __forceinline__ unsigned short f2bf(float f) {
  union { float f; unsigned int u; } v; v.f = f;
  unsigned int r = v.u + 0x7FFFu + ((v.u >> 16) & 1u);
  return (unsigned short)(r >> 16);
}

// ---- one-pass fp32->bf16 casts + zero num/den accumulators ----
__global__ __launch_bounds__(256) void prep(
    const float* __restrict__ hs, const float* __restrict__ Wq,
    const float* __restrict__ Wk, const float* __restrict__ Wv,
    const float* __restrict__ Wo, unsigned short* __restrict__ hsb,
    unsigned short* __restrict__ Wqkvb, unsigned short* __restrict__ Wob,
    float* __restrict__ numAcc) {
  int b = blockIdx.x;
  const float* src; unsigned short* dst; int base;
  if (b < 384)       { src = hs; dst = hsb;            base = b * 1024; }
  else if (b < 528)  { src = Wq; dst = Wqkvb;          base = (b - 384) * 1024; }
  else if (b < 672)  { src = Wk; dst = Wqkvb + 147456; base = (b - 528) * 1024; }
  else if (b < 1248) { src = Wv; dst = Wqkvb + 294912; base = (b - 672) * 1024; }
  else if (b < 1824) { src = Wo; dst = Wob;            base = (b - 1248) * 1024; }
  else {  // zero numAcc(393216 f) + denAcc(6144 f) contiguous = 99840 float4
    int i = (b - 1824) * 256 + threadIdx.x;
    ((float4*)numAcc)[i] = make_float4(0.f, 0.f, 0.f, 0.f);
    return;
  }
  int i = base + threadIdx.x * 4;
  float4 x = *(const float4*)&src[i];
  ushort4 o;
  o.x = f2bf(x.x); o.y = f2bf(x.y); o.z = f2bf(x.z); o.w = f2bf(x.w);
  *(ushort4*)&dst[i] = o;
}

// ---- QKV GEMM: 32(M)x32(N) tile, split-K x4 (4 MFMA / 4 loads per k-iter).
// Q,K -> QKb[512][384]; V -> Vt[768][512] (transposed).
__global__ __launch_bounds__(256) void gemm_qkv(
    const unsigned short* __restrict__ A, const unsigned short* __restrict__ B,
    unsigned short* __restrict__ QKb, unsigned short* __restrict__ Vt) {
  __shared__ f32x4 part[4][4][64];  // [kpart][subtile][lane]
  const int tid = threadIdx.x;
  const int w = tid >> 6, lane = tid & 63;
  const int lm = lane & 15, quad = lane >> 4;
  const int mt = blockIdx.y * 32;
  const int n0 = blockIdx.x * 32;
  const int kw = w * 192;
  const unsigned short* a_ptr = A + (mt + lm) * 768 + kw + quad * 8;
  const unsigned short* b_ptr = B + (n0 + lm) * 768 + kw + quad * 8;
  f32x4 acc[4] = {{0.f,0.f,0.f,0.f},{0.f,0.f,0.f,0.f},{0.f,0.f,0.f,0.f},{0.f,0.f,0.f,0.f}};
#pragma unroll
  for (int kb = 0; kb < 192; kb += 32) {
    bf16x8 a0 = *(const bf16x8*)(a_ptr + kb);
    bf16x8 a1 = *(const bf16x8*)(a_ptr + 16 * 768 + kb);
    bf16x8 b0 = *(const bf16x8*)(b_ptr + kb);
    bf16x8 b1 = *(const bf16x8*)(b_ptr + 16 * 768 + kb);
    acc[0] = __builtin_amdgcn_mfma_f32_16x16x32_bf16(a0, b0, acc[0], 0, 0, 0);
    acc[1] = __builtin_amdgcn_mfma_f32_16x16x32_bf16(a0, b1, acc[1], 0, 0, 0);
    acc[2] = __builtin_amdgcn_mfma_f32_16x16x32_bf16(a1, b0, acc[2], 0, 0, 0);
    acc[3] = __builtin_amdgcn_mfma_f32_16x16x32_bf16(a1, b1, acc[3], 0, 0, 0);
  }
#pragma unroll
  for (int s = 0; s < 4; ++s) part[w][s][lane] = acc[s];
  __syncthreads();
  {
    // wave w reduces subtile w: mi = w>>1, ni = w&1
    const int m = mt + (w >> 1) * 16;
    const int n = n0 + (w & 1) * 16;
    f32x4 s = part[0][w][lane] + part[1][w][lane] + part[2][w][lane] + part[3][w][lane];
    if (n < 384) {
#pragma unroll
      for (int r = 0; r < 4; ++r)
        QKb[(m + quad * 4 + r) * 384 + n + lm] = f2bf(s[r]);
    } else {
      ushort4 o;
      o.x = f2bf(s[0]); o.y = f2bf(s[1]); o.z = f2bf(s[2]); o.w = f2bf(s[3]);
      *(ushort4*)&Vt[(n - 384 + lm) * 512 + m + quad * 4] = o;
    }
  }
}

// ---- causal taylor attention: one (c,sb,h) tile per block, 432 blocks.
// Barrier-free: score-LDS rows are wave-private; V from global Vt; atomics out.
__global__ __launch_bounds__(256) void attn(
    const unsigned short* __restrict__ QKb, const unsigned short* __restrict__ Vt,
    float* __restrict__ numAcc, float* __restrict__ denAcc) {
  int p = blockIdx.x;
  const int h = blockIdx.y, tid = threadIdx.x;
  int c = 0;
  while (p >= c + 1) { p -= c + 1; ++c; }
  const int sb = p;
  const int t0 = c * 64, s0 = sb * 64;
  __shared__ __align__(16) unsigned short scl[64 * 72];
  const int w = tid >> 6, lane = tid & 63;
  const int lm = lane & 15, quad = lane >> 4;
  bf16x8 aq = {0, 0, 0, 0, 0, 0, 0, 0};
  if (quad < 2)
    aq = *(const bf16x8*)&QKb[(t0 + w * 16 + lm) * 384 + h * 16 + quad * 8];
  f32x4 qk[4];
#pragma unroll
  for (int sbt = 0; sbt < 4; ++sbt) {
    bf16x8 bk = {0, 0, 0, 0, 0, 0, 0, 0};
    if (quad < 2)
      bk = *(const bf16x8*)&QKb[(s0 + sbt * 16 + lm) * 384 + 192 + h * 16 + quad * 8];
    f32x4 z = {0.f, 0.f, 0.f, 0.f};
    qk[sbt] = __builtin_amdgcn_mfma_f32_16x16x32_bf16(aq, bk, z, 0, 0, 0);
  }
  float dsum[4] = {0.f, 0.f, 0.f, 0.f};
#pragma unroll
  for (int sbt = 0; sbt < 4; ++sbt) {
#pragma unroll
    for (int r = 0; r < 4; ++r) {
      const int tl = w * 16 + quad * 4 + r;
      const int sl = sbt * 16 + lm;
      float x = qk[sbt][r];
      float val = (s0 + sl <= t0 + tl) ? 1.f + 0.25f * x + 0.03125f * x * x : 0.f;
      dsum[r] += val;
      scl[tl * 72 + sl] = f2bf(val);
    }
  }
  f32x4 av[4] = {{0.f,0.f,0.f,0.f},{0.f,0.f,0.f,0.f},{0.f,0.f,0.f,0.f},{0.f,0.f,0.f,0.f}};
  const unsigned short* vbase = Vt + (h * 64 + lm) * 512;
#pragma unroll
  for (int kb = 0; kb < 2; ++kb) {
    bf16x8 a = *(const bf16x8*)&scl[(w * 16 + lm) * 72 + kb * 32 + quad * 8];
#pragma unroll
    for (int dt = 0; dt < 4; ++dt) {
      bf16x8 b = *(const bf16x8*)&vbase[dt * 16 * 512 + s0 + kb * 32 + quad * 8];
      av[dt] = __builtin_amdgcn_mfma_f32_16x16x32_bf16(a, b, av[dt], 0, 0, 0);
    }
  }
#pragma unroll
  for (int r = 0; r < 4; ++r) {
    float v = dsum[r];
    v += __shfl_xor(v, 1); v += __shfl_xor(v, 2);
    v += __shfl_xor(v, 4); v += __shfl_xor(v, 8);
    if (lm == 0) atomicAdd(&denAcc[(t0 + w * 16 + quad * 4 + r) * 12 + h], v);
  }
#pragma unroll
  for (int dt = 0; dt < 4; ++dt)
#pragma unroll
    for (int r = 0; r < 4; ++r)
      atomicAdd(&numAcc[(t0 + w * 16 + quad * 4 + r) * 768 + h * 64 + dt * 16 + lm],
                av[dt][r]);
}

// ---- out GEMM: 32x32 tile, split-K x4, fused divide+cast on A-fragments ----
__global__ __launch_bounds__(256) void gemm_out(
    const float* __restrict__ numAcc, const float* __restrict__ denAcc,
    const unsigned short* __restrict__ Wob, float* __restrict__ out) {
  __shared__ f32x4 part[4][4][64];
  const int tid = threadIdx.x;
  const int w = tid >> 6, lane = tid & 63;
  const int lm = lane & 15, quad = lane >> 4;
  const int mt = blockIdx.y * 32;
  const int n0 = blockIdx.x * 32;
  const int ta = mt + lm, tb = mt + 16 + lm;
  const int kw = w * 192;
  f32x4 acc[4] = {{0.f,0.f,0.f,0.f},{0.f,0.f,0.f,0.f},{0.f,0.f,0.f,0.f},{0.f,0.f,0.f,0.f}};
#pragma unroll
  for (int kb = 0; kb < 192; kb += 32) {
    const int k0 = kw + kb + quad * 8;
    const int hh = k0 >> 6;
    float inv0 = 1.f / (denAcc[ta * 12 + hh] + 1e-12f);
    float inv1 = 1.f / (denAcc[tb * 12 + hh] + 1e-12f);
    float4 x0 = *(const float4*)&numAcc[ta * 768 + k0];
    float4 x1 = *(const float4*)&numAcc[ta * 768 + k0 + 4];
    float4 y0 = *(const float4*)&numAcc[tb * 768 + k0];
    float4 y1 = *(const float4*)&numAcc[tb * 768 + k0 + 4];
    bf16x8 a0, a1;
    a0[0] = f2bf(x0.x * inv0); a0[1] = f2bf(x0.y * inv0);
    a0[2] = f2bf(x0.z * inv0); a0[3] = f2bf(x0.w * inv0);
    a0[4] = f2bf(x1.x * inv0); a0[5] = f2bf(x1.y * inv0);
    a0[6] = f2bf(x1.z * inv0); a0[7] = f2bf(x1.w * inv0);
    a1[0] = f2bf(y0.x * inv1); a1[1] = f2bf(y0.y * inv1);
    a1[2] = f2bf(y0.z * inv1); a1[3] = f2bf(y0.w * inv1);
    a1[4] = f2bf(y1.x * inv1); a1[5] = f2bf(y1.y * inv1);
    a1[6] = f2bf(y1.z * inv1); a1[7] = f2bf(y1.w * inv1);
    bf16x8 b0 = *(const bf16x8*)&Wob[(n0 + lm) * 768 + k0];
    bf16x8 b1 = *(const bf16x8*)&Wob[(n0 + 16 + lm) * 768 + k0];
    acc[0] = __builtin_amdgcn_mfma_f32_16x16x32_bf16(a0, b0, acc[0], 0, 0, 0);
    acc[1] = __builtin_amdgcn_mfma_f32_16x16x32_bf16(a0, b1, acc[1], 0, 0, 0);
    acc[2] = __builtin_amdgcn_mfma_f32_16x16x32_bf16(a1, b0, acc[2], 0, 0, 0);
    acc[3] = __builtin_amdgcn_mfma_f32_16x16x32_bf16(a1, b1, acc[3], 0, 0, 0);
  }
#pragma unroll
  for (int s = 0; s < 4; ++s) part[w][s][lane] = acc[s];
  __syncthreads();
  {
    const int m = mt + (w >> 1) * 16;
    const int n = n0 + (w & 1) * 16;
    f32x4 s = part[0][w][lane] + part[1][w][lane] + part[2][w][lane] + part[3][w][lane];
#pragma unroll
    for (int r = 0; r < 4; ++r)
      out[(m + quad * 4 + r) * 768 + n + lm] = s[r];
  }
}

extern "C" void kernel_launch(void* const* d_in, const int* in_sizes, int n_in,
                              void* d_out, int out_size, void* d_ws, size_t ws_size,
                              hipStream_t stream) {
  const float* hs = (const float*)d_in[0];
  const float* Wq = (const float*)d_in[1];
  const float* Wk = (const float*)d_in[2];
  const float* Wv = (const float*)d_in[3];
  const float* Wo = (const float*)d_in[4];
  float* out = (float*)d_out;
  float* ws = (float*)d_ws;

  float* numAcc = ws;                                      // 393216 f
  float* denAcc = ws + 393216;                             // 6144 f (contiguous)
  unsigned short* hsb   = (unsigned short*)(ws + 399360);  // 393216 us
  unsigned short* Wqkvb = hsb + 393216;                    // 884736 us
  unsigned short* Wob   = Wqkvb + 884736;                  // 589824 us
  unsigned short* QKb   = Wob + 589824;                    // 196608 us
  unsigned short* Vt    = QKb + 196608;                    // 393216 us

  // casts + accumulator zeroing
  prep<<<dim3(2214), 256, 0, stream>>>(hs, Wq, Wk, Wv, Wo, hsb, Wqkvb, Wob, numAcc);
  // QKV projections; V emitted transposed (32x32 tiles)
  gemm_qkv<<<dim3(36, 16), 256, 0, stream>>>(hsb, Wqkvb, QKb, Vt);
  // causal taylor attention partials (432 blocks, barrier-free, atomics)
  attn<<<dim3(36, 12), 256, 0, stream>>>(QKb, Vt, numAcc, denAcc);
  // out = (num/den) @ Wo^T (32x32 tiles)
  gemm_out<<<dim3(24, 16), 256, 0, stream>>>(numAcc, denAcc, Wob, out);
}

// Round 14
// 97.632 us; speedup vs baseline: 2.8683x; 1.0637x over previous
//
#include <hip/hip_runtime.h>

typedef short bf16x8 __attribute__((ext_vector_type(8)));
typedef float f32x4 __attribute__((ext_vector_type(4)));

__device__ __forceinline__ unsigned short f2bf(float f) {
  union { float f; unsigned int u; } v; v.f = f;
  unsigned int r = v.u + 0x7FFFu + ((v.u >> 16) & 1u);
  return (unsigned short)(r >> 16);
}

// ---- one-pass fp32->bf16 casts (no zeroing needed anymore) ----
__global__ __launch_bounds__(256) void prep(
    const float* __restrict__ hs, const float* __restrict__ Wq,
    const float* __restrict__ Wk, const float* __restrict__ Wv,
    const float* __restrict__ Wo, unsigned short* __restrict__ hsb,
    unsigned short* __restrict__ Wqkvb, unsigned short* __restrict__ Wob) {
  int b = blockIdx.x;
  const float* src; unsigned short* dst; int base;
  if (b < 384)       { src = hs; dst = hsb;            base = b * 1024; }
  else if (b < 528)  { src = Wq; dst = Wqkvb;          base = (b - 384) * 1024; }
  else if (b < 672)  { src = Wk; dst = Wqkvb + 147456; base = (b - 528) * 1024; }
  else if (b < 1248) { src = Wv; dst = Wqkvb + 294912; base = (b - 672) * 1024; }
  else               { src = Wo; dst = Wob;            base = (b - 1248) * 1024; }
  int i = base + threadIdx.x * 4;
  float4 x = *(const float4*)&src[i];
  ushort4 o;
  o.x = f2bf(x.x); o.y = f2bf(x.y); o.z = f2bf(x.z); o.w = f2bf(x.w);
  *(ushort4*)&dst[i] = o;
}

// ---- QKV GEMM: 32(M)x32(N) tile, split-K x4 (4 MFMA / 4 loads per k-iter).
// Q,K -> QKb[512][384]; V -> Vt[768][512] (transposed).
__global__ __launch_bounds__(256) void gemm_qkv(
    const unsigned short* __restrict__ A, const unsigned short* __restrict__ B,
    unsigned short* __restrict__ QKb, unsigned short* __restrict__ Vt) {
  __shared__ f32x4 part[4][4][64];  // [kpart][subtile][lane]
  const int tid = threadIdx.x;
  const int w = tid >> 6, lane = tid & 63;
  const int lm = lane & 15, quad = lane >> 4;
  const int mt = blockIdx.y * 32;
  const int n0 = blockIdx.x * 32;
  const int kw = w * 192;
  const unsigned short* a_ptr = A + (mt + lm) * 768 + kw + quad * 8;
  const unsigned short* b_ptr = B + (n0 + lm) * 768 + kw + quad * 8;
  f32x4 acc[4] = {{0.f,0.f,0.f,0.f},{0.f,0.f,0.f,0.f},{0.f,0.f,0.f,0.f},{0.f,0.f,0.f,0.f}};
#pragma unroll
  for (int kb = 0; kb < 192; kb += 32) {
    bf16x8 a0 = *(const bf16x8*)(a_ptr + kb);
    bf16x8 a1 = *(const bf16x8*)(a_ptr + 16 * 768 + kb);
    bf16x8 b0 = *(const bf16x8*)(b_ptr + kb);
    bf16x8 b1 = *(const bf16x8*)(b_ptr + 16 * 768 + kb);
    acc[0] = __builtin_amdgcn_mfma_f32_16x16x32_bf16(a0, b0, acc[0], 0, 0, 0);
    acc[1] = __builtin_amdgcn_mfma_f32_16x16x32_bf16(a0, b1, acc[1], 0, 0, 0);
    acc[2] = __builtin_amdgcn_mfma_f32_16x16x32_bf16(a1, b0, acc[2], 0, 0, 0);
    acc[3] = __builtin_amdgcn_mfma_f32_16x16x32_bf16(a1, b1, acc[3], 0, 0, 0);
  }
#pragma unroll
  for (int s = 0; s < 4; ++s) part[w][s][lane] = acc[s];
  __syncthreads();
  {
    const int m = mt + (w >> 1) * 16;
    const int n = n0 + (w & 1) * 16;
    f32x4 s = part[0][w][lane] + part[1][w][lane] + part[2][w][lane] + part[3][w][lane];
    if (n < 384) {
#pragma unroll
      for (int r = 0; r < 4; ++r)
        QKb[(m + quad * 4 + r) * 384 + n + lm] = f2bf(s[r]);
    } else {
      ushort4 o;
      o.x = f2bf(s[0]); o.y = f2bf(s[1]); o.z = f2bf(s[2]); o.w = f2bf(s[3]);
      *(ushort4*)&Vt[(n - 384 + lm) * 512 + m + quad * 4] = o;
    }
  }
}

// ---- causal taylor attention, atomic-free.
// Grid (c=8, h=12, tq=4): block owns 16 t-rows; wave w handles sb = w, w+4,.. <= c,
// accumulating AV in registers; one LDS reduction; single non-atomic store.
__global__ __launch_bounds__(256) void attn(
    const unsigned short* __restrict__ QKb, const unsigned short* __restrict__ Vt,
    float* __restrict__ numAcc, float* __restrict__ denAcc) {
  const int c = blockIdx.x, h = blockIdx.y, tq = blockIdx.z;
  const int tid = threadIdx.x;
  const int w = tid >> 6, lane = tid & 63;
  const int lm = lane & 15, quad = lane >> 4;
  const int t0 = c * 64, tbase = t0 + tq * 16;
  __shared__ __align__(16) unsigned short scl[4][16 * 72];  // per-wave scores
  __shared__ __align__(16) f32x4 partAV[4][4][64];          // [wave][dt][lane]
  __shared__ float denb[4][16];
  // A-fragment (q rows tbase..tbase+16), K=16 zero-padded to 32
  bf16x8 aq = {0, 0, 0, 0, 0, 0, 0, 0};
  if (quad < 2)
    aq = *(const bf16x8*)&QKb[(tbase + lm) * 384 + h * 16 + quad * 8];
  f32x4 av[4] = {{0.f,0.f,0.f,0.f},{0.f,0.f,0.f,0.f},{0.f,0.f,0.f,0.f},{0.f,0.f,0.f,0.f}};
  float dsum[4] = {0.f, 0.f, 0.f, 0.f};
  const unsigned short* vbase = Vt + (h * 64 + lm) * 512;
  unsigned short* sw = &scl[w][0];
  for (int sb = w; sb <= c; sb += 4) {
    const int s0 = sb * 64;
    f32x4 qk[4];
#pragma unroll
    for (int sbt = 0; sbt < 4; ++sbt) {
      bf16x8 bk = {0, 0, 0, 0, 0, 0, 0, 0};
      if (quad < 2)
        bk = *(const bf16x8*)&QKb[(s0 + sbt * 16 + lm) * 384 + 192 + h * 16 + quad * 8];
      f32x4 z = {0.f, 0.f, 0.f, 0.f};
      qk[sbt] = __builtin_amdgcn_mfma_f32_16x16x32_bf16(aq, bk, z, 0, 0, 0);
    }
#pragma unroll
    for (int sbt = 0; sbt < 4; ++sbt) {
#pragma unroll
      for (int r = 0; r < 4; ++r) {
        const int tl = tbase + quad * 4 + r;       // global t
        const int sl = sbt * 16 + lm;              // s within tile
        float x = qk[sbt][r];
        float val = (s0 + sl <= tl) ? 1.f + 0.25f * x + 0.03125f * x * x : 0.f;
        dsum[r] += val;
        sw[(quad * 4 + r) * 72 + sl] = f2bf(val);
      }
    }
#pragma unroll
    for (int kb = 0; kb < 2; ++kb) {
      bf16x8 a = *(const bf16x8*)&sw[lm * 72 + kb * 32 + quad * 8];
#pragma unroll
      for (int dt = 0; dt < 4; ++dt) {
        bf16x8 b = *(const bf16x8*)&vbase[dt * 16 * 512 + s0 + kb * 32 + quad * 8];
        av[dt] = __builtin_amdgcn_mfma_f32_16x16x32_bf16(a, b, av[dt], 0, 0, 0);
      }
    }
  }
  // den row-partials: reduce over lm lanes within each quad-row
#pragma unroll
  for (int r = 0; r < 4; ++r) {
    float v = dsum[r];
    v += __shfl_xor(v, 1); v += __shfl_xor(v, 2);
    v += __shfl_xor(v, 4); v += __shfl_xor(v, 8);
    if (lm == 0) denb[w][quad * 4 + r] = v;
  }
#pragma unroll
  for (int dt = 0; dt < 4; ++dt) partAV[w][dt][lane] = av[dt];
  __syncthreads();
  if (tid < 16)
    denAcc[(tbase + tid) * 12 + h] =
        denb[0][tid] + denb[1][tid] + denb[2][tid] + denb[3][tid];
  {
    // wave w writes d-tile dt=w
    f32x4 s = partAV[0][w][lane] + partAV[1][w][lane] +
              partAV[2][w][lane] + partAV[3][w][lane];
#pragma unroll
    for (int r = 0; r < 4; ++r)
      numAcc[(tbase + quad * 4 + r) * 768 + h * 64 + w * 16 + lm] = s[r];
  }
}

// ---- out GEMM: 32x32 tile, split-K x4, fused divide+cast on A-fragments ----
__global__ __launch_bounds__(256) void gemm_out(
    const float* __restrict__ numAcc, const float* __restrict__ denAcc,
    const unsigned short* __restrict__ Wob, float* __restrict__ out) {
  __shared__ f32x4 part[4][4][64];
  const int tid = threadIdx.x;
  const int w = tid >> 6, lane = tid & 63;
  const int lm = lane & 15, quad = lane >> 4;
  const int mt = blockIdx.y * 32;
  const int n0 = blockIdx.x * 32;
  const int ta = mt + lm, tb = mt + 16 + lm;
  const int kw = w * 192;
  f32x4 acc[4] = {{0.f,0.f,0.f,0.f},{0.f,0.f,0.f,0.f},{0.f,0.f,0.f,0.f},{0.f,0.f,0.f,0.f}};
#pragma unroll
  for (int kb = 0; kb < 192; kb += 32) {
    const int k0 = kw + kb + quad * 8;
    const int hh = k0 >> 6;
    float inv0 = 1.f / (denAcc[ta * 12 + hh] + 1e-12f);
    float inv1 = 1.f / (denAcc[tb * 12 + hh] + 1e-12f);
    float4 x0 = *(const float4*)&numAcc[ta * 768 + k0];
    float4 x1 = *(const float4*)&numAcc[ta * 768 + k0 + 4];
    float4 y0 = *(const float4*)&numAcc[tb * 768 + k0];
    float4 y1 = *(const float4*)&numAcc[tb * 768 + k0 + 4];
    bf16x8 a0, a1;
    a0[0] = f2bf(x0.x * inv0); a0[1] = f2bf(x0.y * inv0);
    a0[2] = f2bf(x0.z * inv0); a0[3] = f2bf(x0.w * inv0);
    a0[4] = f2bf(x1.x * inv0); a0[5] = f2bf(x1.y * inv0);
    a0[6] = f2bf(x1.z * inv0); a0[7] = f2bf(x1.w * inv0);
    a1[0] = f2bf(y0.x * inv1); a1[1] = f2bf(y0.y * inv1);
    a1[2] = f2bf(y0.z * inv1); a1[3] = f2bf(y0.w * inv1);
    a1[4] = f2bf(y1.x * inv1); a1[5] = f2bf(y1.y * inv1);
    a1[6] = f2bf(y1.z * inv1); a1[7] = f2bf(y1.w * inv1);
    bf16x8 b0 = *(const bf16x8*)&Wob[(n0 + lm) * 768 + k0];
    bf16x8 b1 = *(const bf16x8*)&Wob[(n0 + 16 + lm) * 768 + k0];
    acc[0] = __builtin_amdgcn_mfma_f32_16x16x32_bf16(a0, b0, acc[0], 0, 0, 0);
    acc[1] = __builtin_amdgcn_mfma_f32_16x16x32_bf16(a0, b1, acc[1], 0, 0, 0);
    acc[2] = __builtin_amdgcn_mfma_f32_16x16x32_bf16(a1, b0, acc[2], 0, 0, 0);
    acc[3] = __builtin_amdgcn_mfma_f32_16x16x32_bf16(a1, b1, acc[3], 0, 0, 0);
  }
#pragma unroll
  for (int s = 0; s < 4; ++s) part[w][s][lane] = acc[s];
  __syncthreads();
  {
    const int m = mt + (w >> 1) * 16;
    const int n = n0 + (w & 1) * 16;
    f32x4 s = part[0][w][lane] + part[1][w][lane] + part[2][w][lane] + part[3][w][lane];
#pragma unroll
    for (int r = 0; r < 4; ++r)
      out[(m + quad * 4 + r) * 768 + n + lm] = s[r];
  }
}

extern "C" void kernel_launch(void* const* d_in, const int* in_sizes, int n_in,
                              void* d_out, int out_size, void* d_ws, size_t ws_size,
                              hipStream_t stream) {
  const float* hs = (const float*)d_in[0];
  const float* Wq = (const float*)d_in[1];
  const float* Wk = (const float*)d_in[2];
  const float* Wv = (const float*)d_in[3];
  const float* Wo = (const float*)d_in[4];
  float* out = (float*)d_out;
  float* ws = (float*)d_ws;

  float* numAcc = ws;                                      // 393216 f
  float* denAcc = ws + 393216;                             // 6144 f
  unsigned short* hsb   = (unsigned short*)(ws + 399360);  // 393216 us
  unsigned short* Wqkvb = hsb + 393216;                    // 884736 us
  unsigned short* Wob   = Wqkvb + 884736;                  // 589824 us
  unsigned short* QKb   = Wob + 589824;                    // 196608 us
  unsigned short* Vt    = QKb + 196608;                    // 393216 us

  // casts (no zeroing needed: attn writes num/den fully, non-atomically)
  prep<<<dim3(1824), 256, 0, stream>>>(hs, Wq, Wk, Wv, Wo, hsb, Wqkvb, Wob);
  // QKV projections; V emitted transposed (32x32 tiles)
  gemm_qkv<<<dim3(36, 16), 256, 0, stream>>>(hsb, Wqkvb, QKb, Vt);
  // causal taylor attention (384 blocks, register-accumulated, no atomics)
  attn<<<dim3(8, 12, 4), 256, 0, stream>>>(QKb, Vt, numAcc, denAcc);
  // out = (num/den) @ Wo^T (32x32 tiles)
  gemm_out<<<dim3(24, 16), 256, 0, stream>>>(numAcc, denAcc, Wob, out);
}

// Round 15
// 93.374 us; speedup vs baseline: 2.9991x; 1.0456x over previous
//
#include <hip/hip_runtime.h>

typedef short bf16x8 __attribute__((ext_vector_type(8)));
typedef float f32x4 __attribute__((ext_vector_type(4)));

__device__ __forceinline__ unsigned short f2bf(float f) {
  union { float f; unsigned int u; } v; v.f = f;
  unsigned int r = v.u + 0x7FFFu + ((v.u >> 16) & 1u);
  return (unsigned short)(r >> 16);
}

// ---- one-pass fp32->bf16 casts ----
__global__ __launch_bounds__(256) void prep(
    const float* __restrict__ hs, const float* __restrict__ Wq,
    const float* __restrict__ Wk, const float* __restrict__ Wv,
    const float* __restrict__ Wo, unsigned short* __restrict__ hsb,
    unsigned short* __restrict__ Wqkvb, unsigned short* __restrict__ Wob) {
  int b = blockIdx.x;
  const float* src; unsigned short* dst; int base;
  if (b < 384)       { src = hs; dst = hsb;            base = b * 1024; }
  else if (b < 528)  { src = Wq; dst = Wqkvb;          base = (b - 384) * 1024; }
  else if (b < 672)  { src = Wk; dst = Wqkvb + 147456; base = (b - 528) * 1024; }
  else if (b < 1248) { src = Wv; dst = Wqkvb + 294912; base = (b - 672) * 1024; }
  else               { src = Wo; dst = Wob;            base = (b - 1248) * 1024; }
  int i = base + threadIdx.x * 4;
  float4 x = *(const float4*)&src[i];
  ushort4 o;
  o.x = f2bf(x.x); o.y = f2bf(x.y); o.z = f2bf(x.z); o.w = f2bf(x.w);
  *(ushort4*)&dst[i] = o;
}

// ---- QKV GEMM: 32(M)x32(N) tile, split-K x4 (4 MFMA / 4 loads per k-iter).
// Q,K -> QKb[512][384]; V -> Vt[768][512] (transposed).
__global__ __launch_bounds__(256) void gemm_qkv(
    const unsigned short* __restrict__ A, const unsigned short* __restrict__ B,
    unsigned short* __restrict__ QKb, unsigned short* __restrict__ Vt) {
  __shared__ f32x4 part[4][4][64];  // [kpart][subtile][lane]
  const int tid = threadIdx.x;
  const int w = tid >> 6, lane = tid & 63;
  const int lm = lane & 15, quad = lane >> 4;
  const int mt = blockIdx.y * 32;
  const int n0 = blockIdx.x * 32;
  const int kw = w * 192;
  const unsigned short* a_ptr = A + (mt + lm) * 768 + kw + quad * 8;
  const unsigned short* b_ptr = B + (n0 + lm) * 768 + kw + quad * 8;
  f32x4 acc[4] = {{0.f,0.f,0.f,0.f},{0.f,0.f,0.f,0.f},{0.f,0.f,0.f,0.f},{0.f,0.f,0.f,0.f}};
#pragma unroll
  for (int kb = 0; kb < 192; kb += 32) {
    bf16x8 a0 = *(const bf16x8*)(a_ptr + kb);
    bf16x8 a1 = *(const bf16x8*)(a_ptr + 16 * 768 + kb);
    bf16x8 b0 = *(const bf16x8*)(b_ptr + kb);
    bf16x8 b1 = *(const bf16x8*)(b_ptr + 16 * 768 + kb);
    acc[0] = __builtin_amdgcn_mfma_f32_16x16x32_bf16(a0, b0, acc[0], 0, 0, 0);
    acc[1] = __builtin_amdgcn_mfma_f32_16x16x32_bf16(a0, b1, acc[1], 0, 0, 0);
    acc[2] = __builtin_amdgcn_mfma_f32_16x16x32_bf16(a1, b0, acc[2], 0, 0, 0);
    acc[3] = __builtin_amdgcn_mfma_f32_16x16x32_bf16(a1, b1, acc[3], 0, 0, 0);
  }
#pragma unroll
  for (int s = 0; s < 4; ++s) part[w][s][lane] = acc[s];
  __syncthreads();
  {
    const int m = mt + (w >> 1) * 16;
    const int n = n0 + (w & 1) * 16;
    f32x4 s = part[0][w][lane] + part[1][w][lane] + part[2][w][lane] + part[3][w][lane];
    if (n < 384) {
#pragma unroll
      for (int r = 0; r < 4; ++r)
        QKb[(m + quad * 4 + r) * 384 + n + lm] = f2bf(s[r]);
    } else {
      ushort4 o;
      o.x = f2bf(s[0]); o.y = f2bf(s[1]); o.z = f2bf(s[2]); o.w = f2bf(s[3]);
      *(ushort4*)&Vt[(n - 384 + lm) * 512 + m + quad * 4] = o;
    }
  }
}

// ---- causal taylor attention, atomic-free, fused divide.
// Grid (c=8, h=12, tq=4): block owns 16 t-rows; wave w handles sb = w, w+4,.. <= c,
// accumulating AV in registers; LDS reduction; emits Yb = bf16(num/den) directly.
__global__ __launch_bounds__(256) void attn(
    const unsigned short* __restrict__ QKb, const unsigned short* __restrict__ Vt,
    unsigned short* __restrict__ Yb) {
  const int c = blockIdx.x, h = blockIdx.y, tq = blockIdx.z;
  const int tid = threadIdx.x;
  const int w = tid >> 6, lane = tid & 63;
  const int lm = lane & 15, quad = lane >> 4;
  const int t0 = c * 64, tbase = t0 + tq * 16;
  __shared__ __align__(16) unsigned short scl[4][16 * 72];  // per-wave scores
  __shared__ __align__(16) f32x4 partAV[4][4][64];          // [wave][dt][lane]
  __shared__ float denb[4][16];
  // A-fragment (q rows tbase..tbase+16), K=16 zero-padded to 32
  bf16x8 aq = {0, 0, 0, 0, 0, 0, 0, 0};
  if (quad < 2)
    aq = *(const bf16x8*)&QKb[(tbase + lm) * 384 + h * 16 + quad * 8];
  f32x4 av[4] = {{0.f,0.f,0.f,0.f},{0.f,0.f,0.f,0.f},{0.f,0.f,0.f,0.f},{0.f,0.f,0.f,0.f}};
  float dsum[4] = {0.f, 0.f, 0.f, 0.f};
  const unsigned short* vbase = Vt + (h * 64 + lm) * 512;
  unsigned short* sw = &scl[w][0];
  for (int sb = w; sb <= c; sb += 4) {
    const int s0 = sb * 64;
    f32x4 qk[4];
#pragma unroll
    for (int sbt = 0; sbt < 4; ++sbt) {
      bf16x8 bk = {0, 0, 0, 0, 0, 0, 0, 0};
      if (quad < 2)
        bk = *(const bf16x8*)&QKb[(s0 + sbt * 16 + lm) * 384 + 192 + h * 16 + quad * 8];
      f32x4 z = {0.f, 0.f, 0.f, 0.f};
      qk[sbt] = __builtin_amdgcn_mfma_f32_16x16x32_bf16(aq, bk, z, 0, 0, 0);
    }
#pragma unroll
    for (int sbt = 0; sbt < 4; ++sbt) {
#pragma unroll
      for (int r = 0; r < 4; ++r) {
        const int tl = tbase + quad * 4 + r;       // global t
        const int sl = sbt * 16 + lm;              // s within tile
        float x = qk[sbt][r];
        float val = (s0 + sl <= tl) ? 1.f + 0.25f * x + 0.03125f * x * x : 0.f;
        dsum[r] += val;
        sw[(quad * 4 + r) * 72 + sl] = f2bf(val);
      }
    }
#pragma unroll
    for (int kb = 0; kb < 2; ++kb) {
      bf16x8 a = *(const bf16x8*)&sw[lm * 72 + kb * 32 + quad * 8];
#pragma unroll
      for (int dt = 0; dt < 4; ++dt) {
        bf16x8 b = *(const bf16x8*)&vbase[dt * 16 * 512 + s0 + kb * 32 + quad * 8];
        av[dt] = __builtin_amdgcn_mfma_f32_16x16x32_bf16(a, b, av[dt], 0, 0, 0);
      }
    }
  }
  // den row-partials: reduce over lm lanes within each quad-row
#pragma unroll
  for (int r = 0; r < 4; ++r) {
    float v = dsum[r];
    v += __shfl_xor(v, 1); v += __shfl_xor(v, 2);
    v += __shfl_xor(v, 4); v += __shfl_xor(v, 8);
    if (lm == 0) denb[w][quad * 4 + r] = v;
  }
#pragma unroll
  for (int dt = 0; dt < 4; ++dt) partAV[w][dt][lane] = av[dt];
  __syncthreads();
  {
    // wave w finalizes d-tile dt=w: y = num/den, bf16
    f32x4 s = partAV[0][w][lane] + partAV[1][w][lane] +
              partAV[2][w][lane] + partAV[3][w][lane];
#pragma unroll
    for (int r = 0; r < 4; ++r) {
      const int row = quad * 4 + r;
      float den = denb[0][row] + denb[1][row] + denb[2][row] + denb[3][row] + 1e-12f;
      Yb[(tbase + row) * 768 + h * 64 + w * 16 + lm] = f2bf(s[r] / den);
    }
  }
}

// ---- out GEMM: pure bf16 32x32 tile, split-K x4: out = Yb @ Wo^T ----
__global__ __launch_bounds__(256) void gemm_out(
    const unsigned short* __restrict__ Yb, const unsigned short* __restrict__ Wob,
    float* __restrict__ out) {
  __shared__ f32x4 part[4][4][64];
  const int tid = threadIdx.x;
  const int w = tid >> 6, lane = tid & 63;
  const int lm = lane & 15, quad = lane >> 4;
  const int mt = blockIdx.y * 32;
  const int n0 = blockIdx.x * 32;
  const int kw = w * 192;
  const unsigned short* a_ptr = Yb + (mt + lm) * 768 + kw + quad * 8;
  const unsigned short* b_ptr = Wob + (n0 + lm) * 768 + kw + quad * 8;
  f32x4 acc[4] = {{0.f,0.f,0.f,0.f},{0.f,0.f,0.f,0.f},{0.f,0.f,0.f,0.f},{0.f,0.f,0.f,0.f}};
#pragma unroll
  for (int kb = 0; kb < 192; kb += 32) {
    bf16x8 a0 = *(const bf16x8*)(a_ptr + kb);
    bf16x8 a1 = *(const bf16x8*)(a_ptr + 16 * 768 + kb);
    bf16x8 b0 = *(const bf16x8*)(b_ptr + kb);
    bf16x8 b1 = *(const bf16x8*)(b_ptr + 16 * 768 + kb);
    acc[0] = __builtin_amdgcn_mfma_f32_16x16x32_bf16(a0, b0, acc[0], 0, 0, 0);
    acc[1] = __builtin_amdgcn_mfma_f32_16x16x32_bf16(a0, b1, acc[1], 0, 0, 0);
    acc[2] = __builtin_amdgcn_mfma_f32_16x16x32_bf16(a1, b0, acc[2], 0, 0, 0);
    acc[3] = __builtin_amdgcn_mfma_f32_16x16x32_bf16(a1, b1, acc[3], 0, 0, 0);
  }
#pragma unroll
  for (int s = 0; s < 4; ++s) part[w][s][lane] = acc[s];
  __syncthreads();
  {
    const int m = mt + (w >> 1) * 16;
    const int n = n0 + (w & 1) * 16;
    f32x4 s = part[0][w][lane] + part[1][w][lane] + part[2][w][lane] + part[3][w][lane];
#pragma unroll
    for (int r = 0; r < 4; ++r)
      out[(m + quad * 4 + r) * 768 + n + lm] = s[r];
  }
}

extern "C" void kernel_launch(void* const* d_in, const int* in_sizes, int n_in,
                              void* d_out, int out_size, void* d_ws, size_t ws_size,
                              hipStream_t stream) {
  const float* hs = (const float*)d_in[0];
  const float* Wq = (const float*)d_in[1];
  const float* Wk = (const float*)d_in[2];
  const float* Wv = (const float*)d_in[3];
  const float* Wo = (const float*)d_in[4];
  float* out = (float*)d_out;
  float* ws = (float*)d_ws;

  unsigned short* Yb    = (unsigned short*)ws;             // 393216 us
  unsigned short* hsb   = Yb + 393216;                     // 393216 us
  unsigned short* Wqkvb = hsb + 393216;                    // 884736 us
  unsigned short* Wob   = Wqkvb + 884736;                  // 589824 us
  unsigned short* QKb   = Wob + 589824;                    // 196608 us
  unsigned short* Vt    = QKb + 196608;                    // 393216 us

  // casts
  prep<<<dim3(1824), 256, 0, stream>>>(hs, Wq, Wk, Wv, Wo, hsb, Wqkvb, Wob);
  // QKV projections; V emitted transposed (32x32 tiles)
  gemm_qkv<<<dim3(36, 16), 256, 0, stream>>>(hsb, Wqkvb, QKb, Vt);
  // causal taylor attention -> Yb = bf16(num/den)
  attn<<<dim3(8, 12, 4), 256, 0, stream>>>(QKb, Vt, Yb);
  // out = Yb @ Wo^T (pure bf16 GEMM)
  gemm_out<<<dim3(24, 16), 256, 0, stream>>>(Yb, Wob, out);
}